// Round 1
// baseline (21.891 us; speedup 1.0000x reference)
//
#include <hip/hip_runtime.h>
#include <hip/hip_bf16.h>

// Problem: B=8192, S=8, D=96.
// Math collapses (softmax over axis=1 sums to 1; both einsums are rank-1
// outer products of sequence-sums):
//   out[b,s,d] = dot(x[b,s,:], wvcol) + pos[s] * W      for ALL d
// where wvcol[e] = sum_n Wv[n,e], W = sum_e wvcol[e],
//       pos[s]   = sum_j j*Wp[s,j] + bp[s].

#define Bsz 8192
#define Ssz 8
#define Dsz 96
#define NROWS (Bsz * Ssz)   // 65536

// ---- setup: wvcol[96] -> ws[0..95], posW[8] = pos[s]*W -> ws[96..103] ----
__global__ __launch_bounds__(128) void setup_kernel(
    const float* __restrict__ Wp, const float* __restrict__ bp,
    const float* __restrict__ Wv, float* __restrict__ ws) {
    __shared__ float col[96];
    int t = threadIdx.x;
    if (t < 96) {
        float s = 0.f;
        #pragma unroll 8
        for (int n = 0; n < 96; ++n) s += Wv[n * 96 + t];
        col[t] = s;
        ws[t]  = s;
    }
    __syncthreads();
    if (t == 0) {
        float W = 0.f;
        for (int e = 0; e < 96; ++e) W += col[e];
        for (int s = 0; s < 8; ++s) {
            float pos = bp[s];
            for (int j = 0; j < 8; ++j) pos += (float)j * Wp[s * 8 + j];
            ws[96 + s] = pos * W;
        }
    }
}

// ---- main: 8 lanes per row; each lane handles 12 of the 96 elements ----
__global__ __launch_bounds__(256) void attn_collapse_kernel(
    const float* __restrict__ x, const float* __restrict__ ws,
    float* __restrict__ out) {
    int tid = blockIdx.x * 256 + threadIdx.x;   // 0 .. 524287
    int row = tid >> 3;                          // 0 .. 65535
    int sub = tid & 7;                           // 12-elem chunk within row

    const float4* xr = (const float4*)(x + (size_t)row * 96 + sub * 12);
    const float4* wv = (const float4*)(ws + sub * 12);

    float4 a0 = xr[0], a1 = xr[1], a2 = xr[2];
    float4 w0 = wv[0], w1 = wv[1], w2 = wv[2];

    float dot = a0.x * w0.x + a0.y * w0.y + a0.z * w0.z + a0.w * w0.w
              + a1.x * w1.x + a1.y * w1.y + a1.z * w1.z + a1.w * w1.w
              + a2.x * w2.x + a2.y * w2.y + a2.z * w2.z + a2.w * w2.w;

    // reduce across the 8 lanes of this row (xor masks stay within group)
    dot += __shfl_xor(dot, 1);
    dot += __shfl_xor(dot, 2);
    dot += __shfl_xor(dot, 4);

    float val = dot + ws[96 + (row & 7)];
    float4 v = make_float4(val, val, val, val);

    float4* o = (float4*)(out + (size_t)row * 96 + sub * 12);
    o[0] = v; o[1] = v; o[2] = v;
}

extern "C" void kernel_launch(void* const* d_in, const int* in_sizes, int n_in,
                              void* d_out, int out_size, void* d_ws, size_t ws_size,
                              hipStream_t stream) {
    const float* x  = (const float*)d_in[0];
    const float* Wp = (const float*)d_in[1];
    const float* bp = (const float*)d_in[2];
    const float* Wv = (const float*)d_in[3];
    // Wk (d_in[4]) and Wq (d_in[5]) cancel out of the math entirely.
    float* out = (float*)d_out;
    float* ws  = (float*)d_ws;

    setup_kernel<<<1, 128, 0, stream>>>(Wp, bp, Wv, ws);

    int threads = NROWS * 8;                 // 524288
    attn_collapse_kernel<<<threads / 256, 256, 0, stream>>>(x, ws, out);
}

// Round 2
// 17.969 us; speedup vs baseline: 1.2182x; 1.2182x over previous
//
#include <hip/hip_runtime.h>
#include <hip/hip_bf16.h>

// Problem: B=8192, S=8, D=96.
// Math collapses (softmax over axis=1 sums to 1; both einsums are rank-1
// outer products of sequence-sums):
//   out[b,s,d] = sum_e (x[b,s,e] + pos[s]) * col[e]      for ALL d
// where col[e] = sum_n Wv[n,e],
//       pos[s] = sum_j j*Wp[s,j] + bp[s].
// Wk, Wq, softmax, and both einsums cancel. Single fused kernel; each block
// recomputes the tiny setup (coalesced L2-resident reads) so there is no
// second launch and no serial single-thread phase.

#define NROWS (8192 * 8)          // 65536 rows of 96 floats
#define NCHUNK (NROWS * 8)        // 524288 (row, sub) chunks, 12 floats each
#define NBLK 1024
#define NTHR 256
#define STRIDE (NBLK * NTHR)      // 262144; each thread does 2 chunks

__global__ __launch_bounds__(NTHR) void attn_fused_kernel(
    const float* __restrict__ x, const float* __restrict__ Wp,
    const float* __restrict__ bp, const float* __restrict__ Wv,
    float* __restrict__ out) {
    __shared__ __align__(16) float col[96];
    __shared__ float posv[8];

    const int t = threadIdx.x;
    const int tid0 = blockIdx.x * NTHR + t;
    const int tid1 = tid0 + STRIDE;

    // ---- issue x loads FIRST so HBM latency hides under the setup phase ----
    const int row0 = tid0 >> 3, sub0 = tid0 & 7;
    const int row1 = tid1 >> 3, sub1 = tid1 & 7;
    const float4* xr0 = (const float4*)(x + (size_t)row0 * 96 + sub0 * 12);
    const float4* xr1 = (const float4*)(x + (size_t)row1 * 96 + sub1 * 12);
    float4 a0 = xr0[0], a1 = xr0[1], a2 = xr0[2];
    float4 b0 = xr1[0], b1 = xr1[1], b2 = xr1[2];

    // ---- per-block setup: col[96] (coalesced across lanes) + pos[8] ----
    if (t < 96) {
        float s = 0.f;
        #pragma unroll 16
        for (int n = 0; n < 96; ++n) s += Wv[n * 96 + t];
        col[t] = s;
    } else if (t < 104) {
        const int s = t - 96;
        float p = bp[s];
        #pragma unroll
        for (int j = 1; j < 8; ++j) p += (float)j * Wp[s * 8 + j];
        posv[s] = p;
    }
    __syncthreads();

    // ---- chunk 0 ----
    {
        const float4* wv = (const float4*)(col + sub0 * 12);
        float4 w0 = wv[0], w1 = wv[1], w2 = wv[2];
        const float p = posv[row0 & 7];
        float dot = (a0.x + p) * w0.x + (a0.y + p) * w0.y + (a0.z + p) * w0.z + (a0.w + p) * w0.w
                  + (a1.x + p) * w1.x + (a1.y + p) * w1.y + (a1.z + p) * w1.z + (a1.w + p) * w1.w
                  + (a2.x + p) * w2.x + (a2.y + p) * w2.y + (a2.z + p) * w2.z + (a2.w + p) * w2.w;
        dot += __shfl_xor(dot, 1);
        dot += __shfl_xor(dot, 2);
        dot += __shfl_xor(dot, 4);
        float4 v = make_float4(dot, dot, dot, dot);
        float4* o = (float4*)(out + (size_t)row0 * 96 + sub0 * 12);
        o[0] = v; o[1] = v; o[2] = v;
    }
    // ---- chunk 1 ----
    {
        const float4* wv = (const float4*)(col + sub1 * 12);
        float4 w0 = wv[0], w1 = wv[1], w2 = wv[2];
        const float p = posv[row1 & 7];
        float dot = (b0.x + p) * w0.x + (b0.y + p) * w0.y + (b0.z + p) * w0.z + (b0.w + p) * w0.w
                  + (b1.x + p) * w1.x + (b1.y + p) * w1.y + (b1.z + p) * w1.z + (b1.w + p) * w1.w
                  + (b2.x + p) * w2.x + (b2.y + p) * w2.y + (b2.z + p) * w2.z + (b2.w + p) * w2.w;
        dot += __shfl_xor(dot, 1);
        dot += __shfl_xor(dot, 2);
        dot += __shfl_xor(dot, 4);
        float4 v = make_float4(dot, dot, dot, dot);
        float4* o = (float4*)(out + (size_t)row1 * 96 + sub1 * 12);
        o[0] = v; o[1] = v; o[2] = v;
    }
}

extern "C" void kernel_launch(void* const* d_in, const int* in_sizes, int n_in,
                              void* d_out, int out_size, void* d_ws, size_t ws_size,
                              hipStream_t stream) {
    const float* x  = (const float*)d_in[0];
    const float* Wp = (const float*)d_in[1];
    const float* bp = (const float*)d_in[2];
    const float* Wv = (const float*)d_in[3];
    // Wk (d_in[4]) and Wq (d_in[5]) cancel out of the math entirely.
    float* out = (float*)d_out;

    attn_fused_kernel<<<NBLK, NTHR, 0, stream>>>(x, Wp, bp, Wv, out);
}

// Round 3
// 13.872 us; speedup vs baseline: 1.5780x; 1.2954x over previous
//
#include <hip/hip_runtime.h>
#include <hip/hip_bf16.h>

// Problem: B=8192, S=8, D=96.
// Math collapses (softmax over axis=1 sums to 1; both einsums are rank-1
// outer products of sequence-sums):
//   out[b,s,d] = sum_e (x[b,s,e] + pos[s]) * col[e]      for ALL d
// where col[e] = sum_n Wv[n,e],  pos[s] = sum_j j*Wp[s,j] + bp[s].
// Wk, Wq, softmax, and both einsums cancel.
//
// Single fused kernel, 256 blocks x 1024 threads (1 block/CU, no tail).
// Per-block setup is parallelized: 768 threads sum 3 rows of Wv each
// (coalesced float4), LDS tree-reduce -> col[96]. x loads are issued
// before setup so HBM latency hides under it. Interleaved layout: the
// 8 lanes of a row each take float4s at sub*4 + j*32, so every 8-lane
// load/store instruction is one contiguous 128B line.

#define NTHR 1024
#define NBLK 256          // 256 blocks * 1024 thr * 2 chunks = 524288 = 65536 rows * 8

__global__ __launch_bounds__(NTHR) void attn_fused_kernel(
    const float* __restrict__ x, const float* __restrict__ Wp,
    const float* __restrict__ bp, const float* __restrict__ Wv,
    float* __restrict__ out) {
    __shared__ __align__(16) float4 part[32][24];   // 12 KB
    __shared__ __align__(16) float4 col4[24];       // col[96]
    __shared__ float posv[8];

    const int t = threadIdx.x;

    // Block-contiguous chunk assignment: block handles chunks
    // [bid*2048, bid*2048+2048); thread does c0 = bid*2048+t, c1 = c0+1024.
    const int c0 = blockIdx.x * (2 * NTHR) + t;
    const int c1 = c0 + NTHR;
    const int row0 = c0 >> 3, sub0 = c0 & 7;
    const int row1 = c1 >> 3, sub1 = c1 & 7;

    // ---- issue x loads FIRST (latency hides under setup) ----
    const float* xb0 = x + (size_t)row0 * 96 + sub0 * 4;
    const float* xb1 = x + (size_t)row1 * 96 + sub1 * 4;
    float4 a0 = *(const float4*)(xb0);
    float4 a1 = *(const float4*)(xb0 + 32);
    float4 a2 = *(const float4*)(xb0 + 64);
    float4 b0 = *(const float4*)(xb1);
    float4 b1 = *(const float4*)(xb1 + 32);
    float4 b2 = *(const float4*)(xb1 + 64);

    // ---- parallel setup: col[e] = sum_n Wv[n,e] ----
    const float4* Wv4 = (const float4*)Wv;          // [96 rows][24 slots]
    if (t < 768) {
        const int slot = t % 24;
        const int g    = t / 24;                    // 0..31, 3 rows each
        const int n0   = g * 3;
        float4 s0 = Wv4[(n0 + 0) * 24 + slot];
        float4 s1 = Wv4[(n0 + 1) * 24 + slot];
        float4 s2 = Wv4[(n0 + 2) * 24 + slot];
        part[g][slot] = make_float4(s0.x + s1.x + s2.x, s0.y + s1.y + s2.y,
                                    s0.z + s1.z + s2.z, s0.w + s1.w + s2.w);
    } else if (t < 776) {
        const int s = t - 768;
        float p = bp[s];
        #pragma unroll
        for (int j = 1; j < 8; ++j) p += (float)j * Wp[s * 8 + j];
        posv[s] = p;
    }
    __syncthreads();
    if (t < 24) {
        float4 c = part[0][t];
        #pragma unroll
        for (int g = 1; g < 32; ++g) {
            float4 q = part[g][t];
            c.x += q.x; c.y += q.y; c.z += q.z; c.w += q.w;
        }
        col4[t] = c;
    }
    __syncthreads();

    // ---- chunk 0 ----
    {
        float4 w0 = col4[sub0 + 0], w1 = col4[sub0 + 8], w2 = col4[sub0 + 16];
        const float p = posv[row0 & 7];
        float dot = (a0.x + p) * w0.x + (a0.y + p) * w0.y + (a0.z + p) * w0.z + (a0.w + p) * w0.w
                  + (a1.x + p) * w1.x + (a1.y + p) * w1.y + (a1.z + p) * w1.z + (a1.w + p) * w1.w
                  + (a2.x + p) * w2.x + (a2.y + p) * w2.y + (a2.z + p) * w2.z + (a2.w + p) * w2.w;
        dot += __shfl_xor(dot, 1);
        dot += __shfl_xor(dot, 2);
        dot += __shfl_xor(dot, 4);
        float4 v = make_float4(dot, dot, dot, dot);
        float* ob = out + (size_t)row0 * 96 + sub0 * 4;
        *(float4*)(ob)      = v;
        *(float4*)(ob + 32) = v;
        *(float4*)(ob + 64) = v;
    }
    // ---- chunk 1 ----
    {
        float4 w0 = col4[sub1 + 0], w1 = col4[sub1 + 8], w2 = col4[sub1 + 16];
        const float p = posv[row1 & 7];
        float dot = (b0.x + p) * w0.x + (b0.y + p) * w0.y + (b0.z + p) * w0.z + (b0.w + p) * w0.w
                  + (b1.x + p) * w1.x + (b1.y + p) * w1.y + (b1.z + p) * w1.z + (b1.w + p) * w1.w
                  + (b2.x + p) * w2.x + (b2.y + p) * w2.y + (b2.z + p) * w2.z + (b2.w + p) * w2.w;
        dot += __shfl_xor(dot, 1);
        dot += __shfl_xor(dot, 2);
        dot += __shfl_xor(dot, 4);
        float4 v = make_float4(dot, dot, dot, dot);
        float* ob = out + (size_t)row1 * 96 + sub1 * 4;
        *(float4*)(ob)      = v;
        *(float4*)(ob + 32) = v;
        *(float4*)(ob + 64) = v;
    }
}

extern "C" void kernel_launch(void* const* d_in, const int* in_sizes, int n_in,
                              void* d_out, int out_size, void* d_ws, size_t ws_size,
                              hipStream_t stream) {
    const float* x  = (const float*)d_in[0];
    const float* Wp = (const float*)d_in[1];
    const float* bp = (const float*)d_in[2];
    const float* Wv = (const float*)d_in[3];
    // Wk (d_in[4]) and Wq (d_in[5]) cancel out of the math entirely.
    float* out = (float*)d_out;

    attn_fused_kernel<<<NBLK, NTHR, 0, stream>>>(x, Wp, bp, Wv, out);
}